// Round 8
// baseline (942.767 us; speedup 1.0000x reference)
//
#include <hip/hip_runtime.h>
#include <hip/hip_bf16.h>
#include <hip/hip_cooperative_groups.h>

namespace cg = cooperative_groups;

#define N_NODES 10000
#define N_EDGES 160000
#define D_IN 512
#define D_OUT 512
#define K_TOT 1024   // concat [x | neigh]
#define BK 64

typedef __attribute__((ext_vector_type(8))) short short8;
typedef __attribute__((ext_vector_type(4))) float f32x4;

__device__ __forceinline__ void load_lds16(const void* g, void* l) {
    __builtin_amdgcn_global_load_lds(
        (const __attribute__((address_space(1))) void*)g,
        (__attribute__((address_space(3))) void*)l, 16, 0, 0);
}

__device__ __forceinline__ float bf16_to_f32(unsigned short u) {
    union { unsigned int i; float f; } c;
    c.i = ((unsigned int)u) << 16;
    return c.f;
}

// ================= MEGA KERNEL (cooperative): 2048 blocks x 256 threads =================
// P0 {zero deg | W-transpose | convert_x} | P1 count | P2 scan | P3 scatter | P4 aggregate
// Wide geometry: 8192 waves for the latency-bound gather phase.

__global__ __launch_bounds__(256, 8) void mega_kernel(
    const float* __restrict__ x,
    const int* __restrict__ src,
    const int* __restrict__ dst,
    const float* __restrict__ Wself,
    const float* __restrict__ Wneigh,
    __hip_bfloat16* __restrict__ Wt,
    __hip_bfloat16* __restrict__ A,
    int* __restrict__ deg,
    int* __restrict__ offsets,
    int* __restrict__ cursor,
    int* __restrict__ csr_src)
{
    cg::grid_group grid = cg::this_grid();
    const int tid = threadIdx.x;
    const int bid = blockIdx.x;
    const int g = bid * 256 + tid;                 // 0 .. 524287
    const int GSZ = 2048 * 256;

    __shared__ float tl[32][33];
    __shared__ int wsum[4];

    // ---------- P0: zero deg; W transpose (blocks 0..511, one 32x32 tile each); convert_x
    if (g < N_NODES) deg[g] = 0;

    if (bid < 512) {
        const int kt0 = (bid & 31) * 32;
        const int nt0 = (bid >> 5) * 32;
        const int tx = tid & 31, ty = tid >> 5;    // ty 0..7
        const float* Wsrc = (kt0 < D_IN) ? (Wself + (size_t)kt0 * D_OUT)
                                         : (Wneigh + (size_t)(kt0 - D_IN) * D_OUT);
#pragma unroll
        for (int p = 0; p < 4; ++p)
            tl[p * 8 + ty][tx] = Wsrc[(size_t)(p * 8 + ty) * D_OUT + nt0 + tx];
        __syncthreads();
#pragma unroll
        for (int p = 0; p < 4; ++p)
            Wt[(size_t)(nt0 + p * 8 + ty) * K_TOT + kt0 + tx] =
                __float2bfloat16(tl[tx][p * 8 + ty]);
    }

    for (int i = g; i < N_NODES * D_IN / 8; i += GSZ) {   // 640000 chunks: 2 rounds
        int row = i >> 6;
        int col = (i & 63) * 8;
        const float4* p = (const float4*)(x + (size_t)row * D_IN + col);
        float4 u = p[0], v = p[1];
        union { short8 s; __hip_bfloat16 h[8]; } o;
        o.h[0] = __float2bfloat16(u.x); o.h[1] = __float2bfloat16(u.y);
        o.h[2] = __float2bfloat16(u.z); o.h[3] = __float2bfloat16(u.w);
        o.h[4] = __float2bfloat16(v.x); o.h[5] = __float2bfloat16(v.y);
        o.h[6] = __float2bfloat16(v.z); o.h[7] = __float2bfloat16(v.w);
        *(short8*)(A + (size_t)row * K_TOT + col) = o.s;
    }
    grid.sync();

    // ---------- P1: count
    if (g < N_EDGES) atomicAdd(&deg[dst[g]], 1);
    grid.sync();

    // ---------- P2: scan (block 0 only; 40 chunks of 256)
    if (bid == 0) {
        int wave = tid >> 6, lane = tid & 63;
        int running = 0;
        for (int c = 0; c < 40; ++c) {
            int i = c * 256 + tid;
            int v = (i < N_NODES) ? deg[i] : 0;
            int s = v;
#pragma unroll
            for (int off = 1; off < 64; off <<= 1) {
                int t = __shfl_up(s, off);
                if (lane >= off) s += t;
            }
            if (lane == 63) wsum[wave] = s;
            __syncthreads();
            if (wave == 0) {
                int w = (lane < 4) ? wsum[lane] : 0;
#pragma unroll
                for (int off = 1; off < 4; off <<= 1) {
                    int t = __shfl_up(w, off);
                    if (lane >= off) w += t;
                }
                if (lane < 4) wsum[lane] = w;
            }
            __syncthreads();
            int wprefix = (wave > 0) ? wsum[wave - 1] : 0;
            int excl = running + wprefix + s - v;
            if (i < N_NODES) { offsets[i] = excl; cursor[i] = excl; }
            running += wsum[3];
            __syncthreads();
        }
        if (tid == 0) offsets[N_NODES] = running;
    }
    grid.sync();

    // ---------- P3: scatter
    if (g < N_EDGES) {
        int p = atomicAdd(&cursor[dst[g]], 1);
        csr_src[p] = src[g];
    }
    grid.sync();

    // ---------- P4: aggregate — one wave per node, balanced partition, 4-deep ILP
    {
        const int w = g >> 6;                      // 0 .. 8191
        const int lane = tid & 63;
        const int d0 = lane * 8;
        const unsigned short* Au = (const unsigned short*)A;
        const int nstart = (int)(((long long)w * N_NODES) >> 13);
        const int nend   = (int)(((long long)(w + 1) * N_NODES) >> 13);
        for (int node = nstart; node < nend; ++node) {
            int e0 = offsets[node], e1 = offsets[node + 1];
            int cnt = e1 - e0;
            float acc[8];
#pragma unroll
            for (int i = 0; i < 8; ++i) acc[i] = 0.f;
            for (int base = 0; base < cnt; base += 64) {
                int m = cnt - base; if (m > 64) m = 64;
                int idx = (base + lane < cnt) ? csr_src[e0 + base + lane] : 0;
                int j = 0;
                for (; j + 3 < m; j += 4) {
                    int s0 = __shfl(idx, j),     s1 = __shfl(idx, j + 1);
                    int s2 = __shfl(idx, j + 2), s3 = __shfl(idx, j + 3);
                    union { short8 v; unsigned short h[8]; } a0, a1, a2, a3;
                    a0.v = *(const short8*)(Au + (size_t)s0 * K_TOT + d0);
                    a1.v = *(const short8*)(Au + (size_t)s1 * K_TOT + d0);
                    a2.v = *(const short8*)(Au + (size_t)s2 * K_TOT + d0);
                    a3.v = *(const short8*)(Au + (size_t)s3 * K_TOT + d0);
#pragma unroll
                    for (int i = 0; i < 8; ++i) acc[i] += bf16_to_f32(a0.h[i]);
#pragma unroll
                    for (int i = 0; i < 8; ++i) acc[i] += bf16_to_f32(a1.h[i]);
#pragma unroll
                    for (int i = 0; i < 8; ++i) acc[i] += bf16_to_f32(a2.h[i]);
#pragma unroll
                    for (int i = 0; i < 8; ++i) acc[i] += bf16_to_f32(a3.h[i]);
                }
                for (; j < m; ++j) {
                    int s0 = __shfl(idx, j);
                    union { short8 v; unsigned short h[8]; } a0;
                    a0.v = *(const short8*)(Au + (size_t)s0 * K_TOT + d0);
#pragma unroll
                    for (int i = 0; i < 8; ++i) acc[i] += bf16_to_f32(a0.h[i]);
                }
            }
            float inv = 1.0f / fmaxf((float)cnt, 1.0f);
            union { short8 s; __hip_bfloat16 h[8]; } o;
#pragma unroll
            for (int i = 0; i < 8; ++i) o.h[i] = __float2bfloat16(acc[i] * inv);
            *(short8*)(A + (size_t)node * K_TOT + D_IN + d0) = o.s;
        }
    }
}

// ================= FALLBACK PATH (R5 kernels, proven) =================

__global__ __launch_bounds__(256) void k1_count_convw(const int* __restrict__ dst,
                                                      int* __restrict__ deg,
                                                      const float* __restrict__ Wself,
                                                      const float* __restrict__ Wneigh,
                                                      __hip_bfloat16* __restrict__ Wt) {
    int bid = blockIdx.x;
    if (bid < 625) {
        int e = bid * 256 + threadIdx.x;
        atomicAdd(&deg[dst[e]], 1);
        return;
    }
    __shared__ float tl[32][33];
    int b = bid - 625;
    int kt0 = (b & 31) * 32;
    int nt0 = (b >> 5) * 32;
    int tx = threadIdx.x & 31, ty = threadIdx.x >> 5;
    const float* Wsrc = (kt0 < D_IN) ? (Wself + (size_t)kt0 * D_OUT)
                                     : (Wneigh + (size_t)(kt0 - D_IN) * D_OUT);
#pragma unroll
    for (int p = 0; p < 4; ++p)
        tl[p * 8 + ty][tx] = Wsrc[(size_t)(p * 8 + ty) * D_OUT + nt0 + tx];
    __syncthreads();
#pragma unroll
    for (int p = 0; p < 4; ++p)
        Wt[(size_t)(nt0 + p * 8 + ty) * K_TOT + kt0 + tx] =
            __float2bfloat16(tl[tx][p * 8 + ty]);
}

__global__ __launch_bounds__(1024) void k2_scan_convx(const int* __restrict__ deg,
                                                      int* __restrict__ offsets,
                                                      int* __restrict__ cursor,
                                                      const float* __restrict__ x,
                                                      __hip_bfloat16* __restrict__ A) {
    int bid = blockIdx.x;
    int tid = threadIdx.x;
    if (bid == 0) {
        __shared__ int wsum[16];
        int wave = tid >> 6, lane = tid & 63;
        int running = 0;
        for (int c = 0; c < 10; ++c) {
            int i = c * 1024 + tid;
            int v = (i < N_NODES) ? deg[i] : 0;
            int s = v;
#pragma unroll
            for (int off = 1; off < 64; off <<= 1) {
                int t = __shfl_up(s, off);
                if (lane >= off) s += t;
            }
            if (lane == 63) wsum[wave] = s;
            __syncthreads();
            if (wave == 0) {
                int w = (lane < 16) ? wsum[lane] : 0;
#pragma unroll
                for (int off = 1; off < 16; off <<= 1) {
                    int t = __shfl_up(w, off);
                    if (lane >= off) w += t;
                }
                if (lane < 16) wsum[lane] = w;
            }
            __syncthreads();
            int wprefix = (wave > 0) ? wsum[wave - 1] : 0;
            int excl = running + wprefix + s - v;
            if (i < N_NODES) { offsets[i] = excl; cursor[i] = excl; }
            running += wsum[15];
            __syncthreads();
        }
        if (tid == 0) offsets[N_NODES] = running;
    } else {
        int gid = (bid - 1) * 1024 + tid;
        int row = gid >> 6;
        int col = (gid & 63) * 8;
        const float4* p = (const float4*)(x + (size_t)row * D_IN + col);
        float4 u = p[0], v = p[1];
        union { short8 s; __hip_bfloat16 h[8]; } o;
        o.h[0] = __float2bfloat16(u.x); o.h[1] = __float2bfloat16(u.y);
        o.h[2] = __float2bfloat16(u.z); o.h[3] = __float2bfloat16(u.w);
        o.h[4] = __float2bfloat16(v.x); o.h[5] = __float2bfloat16(v.y);
        o.h[6] = __float2bfloat16(v.z); o.h[7] = __float2bfloat16(v.w);
        *(short8*)(A + (size_t)row * K_TOT + col) = o.s;
    }
}

__global__ __launch_bounds__(256) void scatter_kernel(const int* __restrict__ src,
                                                      const int* __restrict__ dst,
                                                      int* __restrict__ cursor,
                                                      int* __restrict__ csr_src) {
    int e = blockIdx.x * 256 + threadIdx.x;
    int p = atomicAdd(&cursor[dst[e]], 1);
    csr_src[p] = src[e];
}

__global__ __launch_bounds__(256) void aggregate_kernel(const int* __restrict__ offsets,
                                                        const int* __restrict__ csr_src,
                                                        __hip_bfloat16* __restrict__ A) {
    int wave = threadIdx.x >> 6, lane = threadIdx.x & 63;
    int node = blockIdx.x * 4 + wave;
    if (node >= N_NODES) return;
    int e0 = offsets[node], e1 = offsets[node + 1];
    int cnt = e1 - e0;
    int d0 = lane * 8;
    const unsigned short* Au = (const unsigned short*)A;
    float acc[8];
#pragma unroll
    for (int i = 0; i < 8; ++i) acc[i] = 0.f;
    for (int base = 0; base < cnt; base += 64) {
        int m = cnt - base; if (m > 64) m = 64;
        int idx = (base + lane < cnt) ? csr_src[e0 + base + lane] : 0;
        int j = 0;
        for (; j + 3 < m; j += 4) {
            int s0 = __shfl(idx, j), s1 = __shfl(idx, j + 1);
            int s2 = __shfl(idx, j + 2), s3 = __shfl(idx, j + 3);
            union { short8 v; unsigned short h[8]; } a, b, c, d;
            a.v = *(const short8*)(Au + (size_t)s0 * K_TOT + d0);
            b.v = *(const short8*)(Au + (size_t)s1 * K_TOT + d0);
            c.v = *(const short8*)(Au + (size_t)s2 * K_TOT + d0);
            d.v = *(const short8*)(Au + (size_t)s3 * K_TOT + d0);
#pragma unroll
            for (int i = 0; i < 8; ++i) acc[i] += bf16_to_f32(a.h[i]);
#pragma unroll
            for (int i = 0; i < 8; ++i) acc[i] += bf16_to_f32(b.h[i]);
#pragma unroll
            for (int i = 0; i < 8; ++i) acc[i] += bf16_to_f32(c.h[i]);
#pragma unroll
            for (int i = 0; i < 8; ++i) acc[i] += bf16_to_f32(d.h[i]);
        }
        for (; j < m; ++j) {
            int s0 = __shfl(idx, j);
            union { short8 v; unsigned short h[8]; } a;
            a.v = *(const short8*)(Au + (size_t)s0 * K_TOT + d0);
#pragma unroll
            for (int i = 0; i < 8; ++i) acc[i] += bf16_to_f32(a.h[i]);
        }
    }
    float inv = 1.0f / fmaxf((float)cnt, 1.0f);
    union { short8 s; __hip_bfloat16 h[8]; } o;
#pragma unroll
    for (int i = 0; i < 8; ++i) o.h[i] = __float2bfloat16(acc[i] * inv);
    *(short8*)(A + (size_t)node * K_TOT + D_IN + d0) = o.s;
}

// ================= GEMM 128x64 tile, BK=64, swizzled LDS =================

__global__ __launch_bounds__(256, 2) void gemm_kernel(const short* __restrict__ A,
                                                      const short* __restrict__ Wt,
                                                      const float* __restrict__ bias,
                                                      float* __restrict__ H) {
    __shared__ __align__(16) short smA[128 * BK];   // 16 KB
    __shared__ __align__(16) short smB[64 * BK];    // 8 KB
    const int tid = threadIdx.x;
    const int wave = tid >> 6, lane = tid & 63;
    const int m0 = blockIdx.x * 128;
    const int n0 = blockIdx.y * 64;
    const int wm = wave >> 1, wn = wave & 1;
    const int rr = lane & 15, kq = lane >> 4;

    const int srow8 = lane >> 3;
    const int sslot = (lane & 7) ^ srow8;

    f32x4 acc[4][2];
#pragma unroll
    for (int i = 0; i < 4; ++i)
#pragma unroll
        for (int j = 0; j < 2; ++j) acc[i][j] = (f32x4){0.f, 0.f, 0.f, 0.f};

    int garow[4];
#pragma unroll
    for (int i = 0; i < 4; ++i) {
        int gr = m0 + (wave + 4 * i) * 8 + srow8;
        garow[i] = (gr > N_NODES - 1) ? N_NODES - 1 : gr;
    }
    int gbrow[2];
#pragma unroll
    for (int i = 0; i < 2; ++i) gbrow[i] = n0 + (wave + 4 * i) * 8 + srow8;

    for (int kt = 0; kt < K_TOT / BK; ++kt) {
        const int kbase = kt * BK + sslot * 8;
#pragma unroll
        for (int i = 0; i < 4; ++i)
            load_lds16(A + (size_t)garow[i] * K_TOT + kbase,
                       (char*)smA + (wave + 4 * i) * 1024);
#pragma unroll
        for (int i = 0; i < 2; ++i)
            load_lds16(Wt + (size_t)gbrow[i] * K_TOT + kbase,
                       (char*)smB + (wave + 4 * i) * 1024);
        __syncthreads();

        short8 afr[2][4], bfr[2][2];
#pragma unroll
        for (int ks = 0; ks < 2; ++ks) {
#pragma unroll
            for (int mf = 0; mf < 4; ++mf) {
                int row = wm * 64 + mf * 16 + rr;
                int slot = (ks * 4 + kq) ^ (row & 7);
                afr[ks][mf] = *(const short8*)&smA[row * 64 + slot * 8];
            }
#pragma unroll
            for (int nf = 0; nf < 2; ++nf) {
                int row = wn * 32 + nf * 16 + rr;
                int slot = (ks * 4 + kq) ^ (row & 7);
                bfr[ks][nf] = *(const short8*)&smB[row * 64 + slot * 8];
            }
        }
#pragma unroll
        for (int ks = 0; ks < 2; ++ks)
#pragma unroll
            for (int mf = 0; mf < 4; ++mf)
#pragma unroll
                for (int nf = 0; nf < 2; ++nf)
                    acc[mf][nf] = __builtin_amdgcn_mfma_f32_16x16x32_bf16(
                        afr[ks][mf], bfr[ks][nf], acc[mf][nf], 0, 0, 0);
        __syncthreads();
    }

#pragma unroll
    for (int mf = 0; mf < 4; ++mf) {
        int row = m0 + wm * 64 + mf * 16 + kq * 4;
#pragma unroll
        for (int nf = 0; nf < 2; ++nf) {
            int col = n0 + wn * 32 + nf * 16 + rr;
            float bv = bias[col];
#pragma unroll
            for (int r = 0; r < 4; ++r) {
                int grow = row + r;
                if (grow < N_NODES) {
                    float v = acc[mf][nf][r] + bv;
                    v = (v >= 0.f) ? v : 0.01f * v;
                    H[(size_t)grow * D_OUT + col] = v;
                }
            }
        }
    }
}

// ================= row-wise L2 normalize (in place) =================

__global__ __launch_bounds__(256) void normalize_kernel(float* __restrict__ H) {
    int wave = threadIdx.x >> 6, lane = threadIdx.x & 63;
    int row = blockIdx.x * 4 + wave;
    if (row >= N_NODES) return;
    float4* p = (float4*)(H + (size_t)row * D_OUT + lane * 8);
    float4 u = p[0], v = p[1];
    float s = u.x * u.x + u.y * u.y + u.z * u.z + u.w * u.w +
              v.x * v.x + v.y * v.y + v.z * v.z + v.w * v.w;
#pragma unroll
    for (int o = 32; o > 0; o >>= 1) s += __shfl_xor(s, o);
    float scale = 1.0f / fmaxf(sqrtf(s), 1e-12f);
    u.x *= scale; u.y *= scale; u.z *= scale; u.w *= scale;
    v.x *= scale; v.y *= scale; v.z *= scale; v.w *= scale;
    p[0] = u; p[1] = v;
}

// ================= launch =================

extern "C" void kernel_launch(void* const* d_in, const int* in_sizes, int n_in,
                              void* d_out, int out_size, void* d_ws, size_t ws_size,
                              hipStream_t stream) {
    const float* x      = (const float*)d_in[0];
    const int*   src    = (const int*)d_in[1];
    const int*   dst    = (const int*)d_in[2];
    const float* Wself  = (const float*)d_in[3];
    const float* Wneigh = (const float*)d_in[4];
    const float* bias   = (const float*)d_in[5];
    float* H = (float*)d_out;

    char* ws = (char*)d_ws;
    int* deg     = (int*)ws;                 // 10000
    int* offsets = deg + N_NODES;            // 10001
    int* cursor  = offsets + N_NODES + 1;    // 10000
    int* csr_src = cursor + N_NODES;         // 160000
    size_t int_bytes = ((size_t)(N_NODES * 3 + 1 + N_EDGES) * 4 + 255) & ~(size_t)255;
    __hip_bfloat16* Abuf = (__hip_bfloat16*)(ws + int_bytes);        // [10000][1024]
    __hip_bfloat16* Wt   = Abuf + (size_t)N_NODES * K_TOT;           // [512][1024]

    void* kargs[] = {
        (void*)&x, (void*)&src, (void*)&dst, (void*)&Wself, (void*)&Wneigh,
        (void*)&Wt, (void*)&Abuf, (void*)&deg, (void*)&offsets,
        (void*)&cursor, (void*)&csr_src
    };
    hipError_t cerr = hipLaunchCooperativeKernel((void*)mega_kernel, dim3(2048), dim3(256),
                                                 kargs, 0, stream);
    if (cerr != hipSuccess) {
        // fallback: proven multi-dispatch path (identical math)
        hipMemsetAsync(deg, 0, N_NODES * sizeof(int), stream);
        k1_count_convw<<<625 + 512, 256, 0, stream>>>(dst, deg, Wself, Wneigh, Wt);
        k2_scan_convx<<<626, 1024, 0, stream>>>(deg, offsets, cursor, x, Abuf);
        scatter_kernel<<<625, 256, 0, stream>>>(src, dst, cursor, csr_src);
        aggregate_kernel<<<2500, 256, 0, stream>>>(offsets, csr_src, Abuf);
    }

    dim3 ggrid((N_NODES + 127) / 128, D_OUT / 64);
    gemm_kernel<<<ggrid, 256, 0, stream>>>((const short*)Abuf, (const short*)Wt, bias, H);

    normalize_kernel<<<2500, 256, 0, stream>>>(H);
}

// Round 9
// 96.173 us; speedup vs baseline: 9.8028x; 9.8028x over previous
//
#include <hip/hip_runtime.h>
#include <hip/hip_bf16.h>

#define N_NODES 10000
#define N_EDGES 160000
#define D_IN 512
#define D_OUT 512
#define K_TOT 1024   // concat [x | neigh]
#define BK 64

typedef __attribute__((ext_vector_type(8))) short short8;
typedef __attribute__((ext_vector_type(4))) float f32x4;

__device__ __forceinline__ void load_lds16(const void* g, void* l) {
    __builtin_amdgcn_global_load_lds(
        (const __attribute__((address_space(1))) void*)g,
        (__attribute__((address_space(3))) void*)l, 16, 0, 0);
}

__device__ __forceinline__ float bf16_to_f32(unsigned short u) {
    union { unsigned int i; float f; } c;
    c.i = ((unsigned int)u) << 16;
    return c.f;
}

// ---------------- K1: count (blocks 0..624) + W transpose (blocks 625..1136) ----------------

__global__ __launch_bounds__(256) void k1_count_convw(const int* __restrict__ dst,
                                                      int* __restrict__ deg,
                                                      const float* __restrict__ Wself,
                                                      const float* __restrict__ Wneigh,
                                                      __hip_bfloat16* __restrict__ Wt) {
    int bid = blockIdx.x;
    if (bid < 625) {
        int e = bid * 256 + threadIdx.x;
        atomicAdd(&deg[dst[e]], 1);
        return;
    }
    __shared__ float tl[32][33];
    int b = bid - 625;
    int kt0 = (b & 31) * 32;
    int nt0 = (b >> 5) * 32;
    int tx = threadIdx.x & 31, ty = threadIdx.x >> 5;
    const float* Wsrc = (kt0 < D_IN) ? (Wself + (size_t)kt0 * D_OUT)
                                     : (Wneigh + (size_t)(kt0 - D_IN) * D_OUT);
#pragma unroll
    for (int p = 0; p < 4; ++p)
        tl[p * 8 + ty][tx] = Wsrc[(size_t)(p * 8 + ty) * D_OUT + nt0 + tx];
    __syncthreads();
#pragma unroll
    for (int p = 0; p < 4; ++p)
        Wt[(size_t)(nt0 + p * 8 + ty) * K_TOT + kt0 + tx] =
            __float2bfloat16(tl[tx][p * 8 + ty]);
}

// ---------------- K2: scan (block 0) + convert_x (blocks 1..625) ----------------

__global__ __launch_bounds__(1024) void k2_scan_convx(const int* __restrict__ deg,
                                                      int* __restrict__ offsets,
                                                      int* __restrict__ cursor,
                                                      const float* __restrict__ x,
                                                      __hip_bfloat16* __restrict__ A) {
    int bid = blockIdx.x;
    int tid = threadIdx.x;
    if (bid == 0) {
        __shared__ int wsum[16];
        int wave = tid >> 6, lane = tid & 63;
        int running = 0;
        for (int c = 0; c < 10; ++c) {
            int i = c * 1024 + tid;
            int v = (i < N_NODES) ? deg[i] : 0;
            int s = v;
#pragma unroll
            for (int off = 1; off < 64; off <<= 1) {
                int t = __shfl_up(s, off);
                if (lane >= off) s += t;
            }
            if (lane == 63) wsum[wave] = s;
            __syncthreads();
            if (wave == 0) {
                int w = (lane < 16) ? wsum[lane] : 0;
#pragma unroll
                for (int off = 1; off < 16; off <<= 1) {
                    int t = __shfl_up(w, off);
                    if (lane >= off) w += t;
                }
                if (lane < 16) wsum[lane] = w;
            }
            __syncthreads();
            int wprefix = (wave > 0) ? wsum[wave - 1] : 0;
            int excl = running + wprefix + s - v;
            if (i < N_NODES) { offsets[i] = excl; cursor[i] = excl; }
            running += wsum[15];
            __syncthreads();
        }
        if (tid == 0) offsets[N_NODES] = running;
    } else {
        int gid = (bid - 1) * 1024 + tid;
        int row = gid >> 6;
        int col = (gid & 63) * 8;
        const float4* p = (const float4*)(x + (size_t)row * D_IN + col);
        float4 u = p[0], v = p[1];
        union { short8 s; __hip_bfloat16 h[8]; } o;
        o.h[0] = __float2bfloat16(u.x); o.h[1] = __float2bfloat16(u.y);
        o.h[2] = __float2bfloat16(u.z); o.h[3] = __float2bfloat16(u.w);
        o.h[4] = __float2bfloat16(v.x); o.h[5] = __float2bfloat16(v.y);
        o.h[6] = __float2bfloat16(v.z); o.h[7] = __float2bfloat16(v.w);
        *(short8*)(A + (size_t)row * K_TOT + col) = o.s;
    }
}

// ---------------- K3: scatter ----------------

__global__ __launch_bounds__(256) void scatter_kernel(const int* __restrict__ src,
                                                      const int* __restrict__ dst,
                                                      int* __restrict__ cursor,
                                                      int* __restrict__ csr_src) {
    int e = blockIdx.x * 256 + threadIdx.x;
    int p = atomicAdd(&cursor[dst[e]], 1);
    csr_src[p] = src[e];
}

// ---------------- K4: aggregation — one wave per node, bf16 gather ----------------

__global__ __launch_bounds__(256) void aggregate_kernel(const int* __restrict__ offsets,
                                                        const int* __restrict__ csr_src,
                                                        __hip_bfloat16* __restrict__ A) {
    int wave = threadIdx.x >> 6, lane = threadIdx.x & 63;
    int node = blockIdx.x * 4 + wave;
    if (node >= N_NODES) return;
    int e0 = offsets[node], e1 = offsets[node + 1];
    int cnt = e1 - e0;
    int d0 = lane * 8;
    const unsigned short* Au = (const unsigned short*)A;
    float acc[8];
#pragma unroll
    for (int i = 0; i < 8; ++i) acc[i] = 0.f;
    for (int base = 0; base < cnt; base += 64) {
        int m = cnt - base; if (m > 64) m = 64;
        int idx = (base + lane < cnt) ? csr_src[e0 + base + lane] : 0;
        int j = 0;
        for (; j + 3 < m; j += 4) {
            int s0 = __shfl(idx, j), s1 = __shfl(idx, j + 1);
            int s2 = __shfl(idx, j + 2), s3 = __shfl(idx, j + 3);
            union { short8 v; unsigned short h[8]; } a, b, c, d;
            a.v = *(const short8*)(Au + (size_t)s0 * K_TOT + d0);
            b.v = *(const short8*)(Au + (size_t)s1 * K_TOT + d0);
            c.v = *(const short8*)(Au + (size_t)s2 * K_TOT + d0);
            d.v = *(const short8*)(Au + (size_t)s3 * K_TOT + d0);
#pragma unroll
            for (int i = 0; i < 8; ++i) acc[i] += bf16_to_f32(a.h[i]);
#pragma unroll
            for (int i = 0; i < 8; ++i) acc[i] += bf16_to_f32(b.h[i]);
#pragma unroll
            for (int i = 0; i < 8; ++i) acc[i] += bf16_to_f32(c.h[i]);
#pragma unroll
            for (int i = 0; i < 8; ++i) acc[i] += bf16_to_f32(d.h[i]);
        }
        for (; j < m; ++j) {
            int s0 = __shfl(idx, j);
            union { short8 v; unsigned short h[8]; } a;
            a.v = *(const short8*)(Au + (size_t)s0 * K_TOT + d0);
#pragma unroll
            for (int i = 0; i < 8; ++i) acc[i] += bf16_to_f32(a.h[i]);
        }
    }
    float inv = 1.0f / fmaxf((float)cnt, 1.0f);
    union { short8 s; __hip_bfloat16 h[8]; } o;
#pragma unroll
    for (int i = 0; i < 8; ++i) o.h[i] = __float2bfloat16(acc[i] * inv);
    *(short8*)(A + (size_t)node * K_TOT + D_IN + d0) = o.s;
}

// ---------------- K5: GEMM 128x64, BK=64, swizzled LDS, double-buffered prefetch,
//                  XCD-clustered 1D grid (632 = 8 x 79, bijective m204 swizzle) ----------------

__global__ __launch_bounds__(256, 2) void gemm_kernel(const short* __restrict__ A,
                                                      const short* __restrict__ Wt,
                                                      const float* __restrict__ bias,
                                                      float* __restrict__ H) {
    __shared__ __align__(16) short smA[2][128 * BK];   // 2 x 16 KB
    __shared__ __align__(16) short smB[2][64 * BK];    // 2 x 8 KB
    const int tid = threadIdx.x;
    const int wave = tid >> 6, lane = tid & 63;

    // XCD-cluster swizzle: blocks sharing an A-panel (same mx) land on one XCD
    const int s = (blockIdx.x & 7) * 79 + (blockIdx.x >> 3);   // bijective, 632=8*79
    const int mx = s >> 3, ny = s & 7;
    const int m0 = mx * 128;
    const int n0 = ny * 64;

    const int wm = wave >> 1, wn = wave & 1;
    const int rr = lane & 15, kq = lane >> 4;

    const int srow8 = lane >> 3;            // row within 8-row chunk
    const int sslot = (lane & 7) ^ srow8;   // pre-swizzled global 16B-chunk index

    f32x4 acc[4][2];
#pragma unroll
    for (int i = 0; i < 4; ++i)
#pragma unroll
        for (int j = 0; j < 2; ++j) acc[i][j] = (f32x4){0.f, 0.f, 0.f, 0.f};

    int garow[4];
#pragma unroll
    for (int i = 0; i < 4; ++i) {
        int gr = m0 + (wave + 4 * i) * 8 + srow8;
        garow[i] = (gr > N_NODES - 1) ? N_NODES - 1 : gr;
    }
    int gbrow[2];
#pragma unroll
    for (int i = 0; i < 2; ++i) gbrow[i] = n0 + (wave + 4 * i) * 8 + srow8;

    auto stage = [&](int buf, int kt) {
        const int kbase = kt * BK + sslot * 8;
#pragma unroll
        for (int i = 0; i < 4; ++i)
            load_lds16(A + (size_t)garow[i] * K_TOT + kbase,
                       (char*)smA[buf] + (wave + 4 * i) * 1024);
#pragma unroll
        for (int i = 0; i < 2; ++i)
            load_lds16(Wt + (size_t)gbrow[i] * K_TOT + kbase,
                       (char*)smB[buf] + (wave + 4 * i) * 1024);
    };

    stage(0, 0);
    __syncthreads();                         // drain prologue loads

    for (int kt = 0; kt < K_TOT / BK; ++kt) {
        const int cur = kt & 1;
        if (kt + 1 < K_TOT / BK) stage(cur ^ 1, kt + 1);   // prefetch next tile

        short8 afr[2][4], bfr[2][2];
#pragma unroll
        for (int ks = 0; ks < 2; ++ks) {
#pragma unroll
            for (int mf = 0; mf < 4; ++mf) {
                int row = wm * 64 + mf * 16 + rr;
                int slot = (ks * 4 + kq) ^ (row & 7);
                afr[ks][mf] = *(const short8*)&smA[cur][row * 64 + slot * 8];
            }
#pragma unroll
            for (int nf = 0; nf < 2; ++nf) {
                int row = wn * 32 + nf * 16 + rr;
                int slot = (ks * 4 + kq) ^ (row & 7);
                bfr[ks][nf] = *(const short8*)&smB[cur][row * 64 + slot * 8];
            }
        }
#pragma unroll
        for (int ks = 0; ks < 2; ++ks)
#pragma unroll
            for (int mf = 0; mf < 4; ++mf)
#pragma unroll
                for (int nf = 0; nf < 2; ++nf)
                    acc[mf][nf] = __builtin_amdgcn_mfma_f32_16x16x32_bf16(
                        afr[ks][mf], bfr[ks][nf], acc[mf][nf], 0, 0, 0);
        __syncthreads();                     // drains prefetch (vmcnt0) after compute
    }

    // epilogue: bias + leaky_relu, store f32.  C/D: col=lane&15, row=(lane>>4)*4+reg
#pragma unroll
    for (int mf = 0; mf < 4; ++mf) {
        int row = m0 + wm * 64 + mf * 16 + kq * 4;
#pragma unroll
        for (int nf = 0; nf < 2; ++nf) {
            int col = n0 + wn * 32 + nf * 16 + rr;
            float bv = bias[col];
#pragma unroll
            for (int r = 0; r < 4; ++r) {
                int grow = row + r;
                if (grow < N_NODES) {
                    float v = acc[mf][nf][r] + bv;
                    v = (v >= 0.f) ? v : 0.01f * v;
                    H[(size_t)grow * D_OUT + col] = v;
                }
            }
        }
    }
}

// ---------------- K6: row-wise L2 normalize (in place) ----------------

__global__ __launch_bounds__(256) void normalize_kernel(float* __restrict__ H) {
    int wave = threadIdx.x >> 6, lane = threadIdx.x & 63;
    int row = blockIdx.x * 4 + wave;
    if (row >= N_NODES) return;
    float4* p = (float4*)(H + (size_t)row * D_OUT + lane * 8);
    float4 u = p[0], v = p[1];
    float s = u.x * u.x + u.y * u.y + u.z * u.z + u.w * u.w +
              v.x * v.x + v.y * v.y + v.z * v.z + v.w * v.w;
#pragma unroll
    for (int o = 32; o > 0; o >>= 1) s += __shfl_xor(s, o);
    float scale = 1.0f / fmaxf(sqrtf(s), 1e-12f);
    u.x *= scale; u.y *= scale; u.z *= scale; u.w *= scale;
    v.x *= scale; v.y *= scale; v.z *= scale; v.w *= scale;
    p[0] = u; p[1] = v;
}

// ---------------- launch ----------------

extern "C" void kernel_launch(void* const* d_in, const int* in_sizes, int n_in,
                              void* d_out, int out_size, void* d_ws, size_t ws_size,
                              hipStream_t stream) {
    const float* x      = (const float*)d_in[0];
    const int*   src    = (const int*)d_in[1];
    const int*   dst    = (const int*)d_in[2];
    const float* Wself  = (const float*)d_in[3];
    const float* Wneigh = (const float*)d_in[4];
    const float* bias   = (const float*)d_in[5];
    float* H = (float*)d_out;

    char* ws = (char*)d_ws;
    int* deg     = (int*)ws;                 // 10000
    int* offsets = deg + N_NODES;            // 10001
    int* cursor  = offsets + N_NODES + 1;    // 10000
    int* csr_src = cursor + N_NODES;         // 160000
    size_t int_bytes = ((size_t)(N_NODES * 3 + 1 + N_EDGES) * 4 + 255) & ~(size_t)255;
    __hip_bfloat16* Abuf = (__hip_bfloat16*)(ws + int_bytes);        // [10000][1024]
    __hip_bfloat16* Wt   = Abuf + (size_t)N_NODES * K_TOT;           // [512][1024]

    hipMemsetAsync(deg, 0, N_NODES * sizeof(int), stream);

    k1_count_convw<<<625 + 512, 256, 0, stream>>>(dst, deg, Wself, Wneigh, Wt);
    k2_scan_convx<<<626, 1024, 0, stream>>>(deg, offsets, cursor, x, Abuf);
    scatter_kernel<<<625, 256, 0, stream>>>(src, dst, cursor, csr_src);
    aggregate_kernel<<<2500, 256, 0, stream>>>(offsets, csr_src, Abuf);

    gemm_kernel<<<632, 256, 0, stream>>>((const short*)Abuf, (const short*)Wt, bias, H);

    normalize_kernel<<<2500, 256, 0, stream>>>(H);
}